// Round 1
// baseline (909.157 us; speedup 1.0000x reference)
//
#include <hip/hip_runtime.h>
#include <stdint.h>

#define SEQ 16384
#define HIDN 1280
#define NHEADS 16
#define HD 80
#define HDP 96
#define NWIN 16
#define WINSZ 1024

typedef unsigned short u16;
typedef unsigned int u32;
typedef __bf16 bf16x8 __attribute__((ext_vector_type(8)));
typedef float f32x4 __attribute__((ext_vector_type(4)));

#define AS1 __attribute__((address_space(1)))
#define AS3 __attribute__((address_space(3)))

__device__ __forceinline__ u16 f2b(float f) {
  u32 u = __float_as_uint(f);
  u += 0x7fffu + ((u >> 16) & 1u);   // RNE
  return (u16)(u >> 16);
}
__device__ __forceinline__ float b2f(u16 u) { return __uint_as_float(((u32)u) << 16); }

__device__ __forceinline__ float fexp2(float x) {
#if __has_builtin(__builtin_amdgcn_exp2f)
  return __builtin_amdgcn_exp2f(x);
#else
  return exp2f(x);
#endif
}

__device__ __forceinline__ void load_lds16(const void* g, void* l) {
  __builtin_amdgcn_global_load_lds((AS1 void*)g, (AS3 void*)l, 16, 0, 0);
}

// ---------------- fp32 -> bf16 flat convert ----------------
__global__ void k_cvt(const float* __restrict__ in, u16* __restrict__ out) {
  size_t i = ((size_t)blockIdx.x * 256 + threadIdx.x) * 4;
  float4 v = *(const float4*)(in + i);
  uint2 o;
  o.x = (u32)f2b(v.x) | ((u32)f2b(v.y) << 16);
  o.y = (u32)f2b(v.z) | ((u32)f2b(v.w) << 16);
  *(uint2*)(out + i) = o;
}

// ---------------- transpose f32 [R][C] -> bf16 [C][R] ----------------
__global__ void k_trans(const float* __restrict__ in, u16* __restrict__ out, int R, int C) {
  __shared__ float tile[64][65];
  int c0 = blockIdx.x * 64, r0 = blockIdx.y * 64;
  int tc = threadIdx.x & 63, tr4 = threadIdx.x >> 6;
#pragma unroll
  for (int i = 0; i < 16; i++) {
    int r = tr4 + i * 4;
    tile[r][tc] = in[(size_t)(r0 + r) * C + c0 + tc];
  }
  __syncthreads();
#pragma unroll
  for (int i = 0; i < 16; i++) {
    int r = tr4 + i * 4;
    out[(size_t)(c0 + r) * R + r0 + tc] = f2b(tile[tc][r]);
  }
}

// ---------------- GEMM: C[M,N] = A[M,K](bf16) * B^T[N,K](bf16) + bias ----------------
// MODE 0: proj -> f32 out.  MODE 1: qkv -> scatter Q/K raw [H][S][96], V -> Vt [H][80][S]
template <int MODE>
__launch_bounds__(256, 2)
__global__ void k_gemm(const u16* __restrict__ A, const u16* __restrict__ B,
                       const float* __restrict__ bias, float* __restrict__ outf,
                       u16* __restrict__ Qb, u16* __restrict__ Kb, u16* __restrict__ Vt,
                       int N, int K) {
  __shared__ char lds[16384];  // A-frags 8KB | B-frags 8KB
  const int tid = threadIdx.x;
  const int wv = tid >> 6, lane = tid & 63;
  const int lr = lane & 15, lq = lane >> 4;
  const int wm = wv >> 1, wn = wv & 1;
  const int row0 = blockIdx.y * 128, col0 = blockIdx.x * 128;

  f32x4 acc[4][4];
#pragma unroll
  for (int i = 0; i < 4; i++)
#pragma unroll
    for (int j = 0; j < 4; j++) acc[i][j] = (f32x4){0.f, 0.f, 0.f, 0.f};

  for (int kk = 0; kk < K; kk += 32) {
#pragma unroll
    for (int i = 0; i < 4; i++) {
      int g = wv * 4 + i;
      const u16* gp;
      char* lp;
      if (g < 8) {
        gp = A + (size_t)(row0 + g * 16 + lr) * K + kk + lq * 8;
        lp = lds + g * 1024;
      } else {
        gp = B + (size_t)(col0 + (g - 8) * 16 + lr) * K + kk + lq * 8;
        lp = lds + 8192 + (g - 8) * 1024;
      }
      load_lds16(gp, lp);
    }
    __syncthreads();
    bf16x8 af[4], bfr[4];
#pragma unroll
    for (int mi = 0; mi < 4; mi++) af[mi] = *(const bf16x8*)(lds + (wm * 4 + mi) * 1024 + lane * 16);
#pragma unroll
    for (int ni = 0; ni < 4; ni++) bfr[ni] = *(const bf16x8*)(lds + 8192 + (wn * 4 + ni) * 1024 + lane * 16);
#pragma unroll
    for (int mi = 0; mi < 4; mi++)
#pragma unroll
      for (int ni = 0; ni < 4; ni++)
        acc[mi][ni] = __builtin_amdgcn_mfma_f32_16x16x32_bf16(af[mi], bfr[ni], acc[mi][ni], 0, 0, 0);
    __syncthreads();
  }

  // epilogue: C/D layout col=lane&15, row=(lane>>4)*4+reg (m89-verified)
#pragma unroll
  for (int ni = 0; ni < 4; ni++) {
    int col = col0 + wn * 64 + ni * 16 + lr;
    float bs = bias[col];
    if (MODE == 0) {
#pragma unroll
      for (int mi = 0; mi < 4; mi++)
#pragma unroll
        for (int r = 0; r < 4; r++) {
          int row = row0 + wm * 64 + mi * 16 + lq * 4 + r;
          outf[(size_t)row * N + col] = acc[mi][ni][r] + bs;
        }
    } else {
      int seg = col / HIDN;            // 0=q 1=k 2=v (uniform per 16-col tile: 1280%16==0)
      int cl = col - seg * HIDN;
      int h = cl / HD, d = cl - h * HD;
#pragma unroll
      for (int mi = 0; mi < 4; mi++)
#pragma unroll
        for (int r = 0; r < 4; r++) {
          int row = row0 + wm * 64 + mi * 16 + lq * 4 + r;
          u16 bv = f2b(acc[mi][ni][r] + bs);
          if (seg == 0)
            Qb[((size_t)h * SEQ + row) * HDP + d] = bv;
          else if (seg == 1)
            Kb[((size_t)h * SEQ + row) * HDP + d] = bv;
          else
            Vt[((size_t)h * HD + d) * SEQ + row] = bv;
        }
    }
  }
}

// ---------------- in-place RoPE on [H][S][96] bf16, zero pad d in [80,96) ----------------
__global__ void k_rope(u16* __restrict__ X, const float* __restrict__ cs, const float* __restrict__ sn) {
  int idx = blockIdx.x * 256 + threadIdx.x;  // [0, 16*16384*40)
  int h = idx / (SEQ * 40);
  int rem = idx - h * (SEQ * 40);
  int s = rem / 40;
  int d = rem - s * 40;
  size_t base = ((size_t)h * SEQ + s) * HDP;
  float c = cs[s * HD + d], si = sn[s * HD + d];  // cos[d]==cos[d+40]
  float x1 = b2f(X[base + d]), x2 = b2f(X[base + d + 40]);
  X[base + d] = f2b(x1 * c - x2 * si);
  X[base + d + 40] = f2b(x2 * c + x1 * si);
  if (d < 16) X[base + 80 + d] = 0;
}

// ---------------- windowed flash attention ----------------
// Q,K: [H][S][96] bf16 (rope'd, pad=0); Vt: [H][80][S] bf16; Ob: [S][1280] bf16
// block: 256 thr = 4 waves, each wave: 32 q (2 tiles), k-tiles of 128 keys
__launch_bounds__(256, 2)
__global__ void k_attn(const u16* __restrict__ Qb, const u16* __restrict__ Kb,
                       const u16* __restrict__ Vt, u16* __restrict__ Ob) {
  __shared__ char lds[24576 + 20480 + 4 * 4352];
  char* ldsK = lds;
  char* ldsV = lds + 24576;
  char* ldsP = lds + 45056;

  const int tid = threadIdx.x;
  const int wv = tid >> 6, lane = tid & 63;
  const int lr = lane & 15, lq = lane >> 4;

  const int b = blockIdx.x;
  const int qblk = b & 7, h = (b >> 3) & 15, w = b >> 7;
  const int q0 = w * WINSZ + qblk * 128 + wv * 32;
  const int kwin = w * WINSZ;

  // resident Q fragments (B-operand of S^T = K*Q^T): Q[q=lane&15][d=quad*8+j]
  bf16x8 qf[2][3];
#pragma unroll
  for (int qt = 0; qt < 2; qt++)
#pragma unroll
    for (int ds = 0; ds < 3; ds++)
      qf[qt][ds] = *(const bf16x8*)(Qb + ((size_t)h * SEQ + q0 + qt * 16 + lr) * HDP + ds * 32 + lq * 8);

  f32x4 acc[2][5];
#pragma unroll
  for (int i = 0; i < 2; i++)
#pragma unroll
    for (int j = 0; j < 5; j++) acc[i][j] = (f32x4){0.f, 0.f, 0.f, 0.f};
  float mo[2] = {-1e30f, -1e30f};
  float lsum[2] = {0.f, 0.f};
  const float kscale = 0.11180339887498949f * 1.4426950408889634f;  // 1/sqrt(80) * log2(e)

  for (int kt = 0; kt < 8; kt++) {
    int k0 = kwin + kt * 128;
    // stage K-tile (24 KB) + Vt-tile (20 KB) in fragment order
#pragma unroll
    for (int li = 0; li < 11; li++) {
      int g = li * 4 + wv;
      const u16* gp;
      char* lp;
      if (g < 24) {
        int kt16 = g / 3, ds = g - kt16 * 3;
        gp = Kb + ((size_t)h * SEQ + k0 + kt16 * 16 + lr) * HDP + ds * 32 + lq * 8;
        lp = ldsK + g * 1024;
      } else {
        int g2 = g - 24;
        int dt = g2 >> 2, ks = g2 & 3;
        gp = Vt + ((size_t)h * HD + dt * 16 + lr) * SEQ + k0 + ks * 32 + lq * 8;
        lp = ldsV + g2 * 1024;
      }
      load_lds16(gp, lp);
    }
    __syncthreads();

    // S^T = K*Q^T  (A=K frag, B=Q frag); S^T[key=quad*4+reg][q=lane&15]
    f32x4 sx[2][8];
#pragma unroll
    for (int i = 0; i < 2; i++)
#pragma unroll
      for (int j = 0; j < 8; j++) sx[i][j] = (f32x4){0.f, 0.f, 0.f, 0.f};
#pragma unroll
    for (int kt16 = 0; kt16 < 8; kt16++) {
      bf16x8 kf0 = *(const bf16x8*)(ldsK + (kt16 * 3 + 0) * 1024 + lane * 16);
      bf16x8 kf1 = *(const bf16x8*)(ldsK + (kt16 * 3 + 1) * 1024 + lane * 16);
      bf16x8 kf2 = *(const bf16x8*)(ldsK + (kt16 * 3 + 2) * 1024 + lane * 16);
#pragma unroll
      for (int qt = 0; qt < 2; qt++) {
        sx[qt][kt16] = __builtin_amdgcn_mfma_f32_16x16x32_bf16(kf0, qf[qt][0], sx[qt][kt16], 0, 0, 0);
        sx[qt][kt16] = __builtin_amdgcn_mfma_f32_16x16x32_bf16(kf1, qf[qt][1], sx[qt][kt16], 0, 0, 0);
        sx[qt][kt16] = __builtin_amdgcn_mfma_f32_16x16x32_bf16(kf2, qf[qt][2], sx[qt][kt16], 0, 0, 0);
      }
    }

    // online softmax (per-lane column q; cross-quad reduce via xor 16/32) + P->LDS->B-frags
    bf16x8 pf[2][4];
#pragma unroll
    for (int qt = 0; qt < 2; qt++) {
      float mx = -1e30f;
#pragma unroll
      for (int t = 0; t < 8; t++)
#pragma unroll
        for (int r = 0; r < 4; r++) mx = fmaxf(mx, sx[qt][t][r]);
      mx = fmaxf(mx, __shfl_xor(mx, 16));
      mx = fmaxf(mx, __shfl_xor(mx, 32));
      float mnew = fmaxf(mo[qt], mx * kscale);
      float alpha = fexp2(mo[qt] - mnew);
      mo[qt] = mnew;
      float ls = 0.f;
#pragma unroll
      for (int t = 0; t < 8; t++)
#pragma unroll
        for (int r = 0; r < 4; r++) {
          float p = fexp2(fmaf(sx[qt][t][r], kscale, -mnew));
          sx[qt][t][r] = p;
          ls += p;
        }
      ls += __shfl_xor(ls, 16);
      ls += __shfl_xor(ls, 32);
      lsum[qt] = lsum[qt] * alpha + ls;
#pragma unroll
      for (int dt = 0; dt < 5; dt++) acc[qt][dt] *= alpha;
      // write P (bf16) to per-wave LDS: rows q (stride 272B), cols key
      char* pw = ldsP + wv * 4352;
#pragma unroll
      for (int t = 0; t < 8; t++) {
        u32 w0 = (u32)f2b(sx[qt][t][0]) | ((u32)f2b(sx[qt][t][1]) << 16);
        u32 w1 = (u32)f2b(sx[qt][t][2]) | ((u32)f2b(sx[qt][t][3]) << 16);
        *(u32*)(pw + lr * 272 + t * 32 + lq * 8) = w0;
        *(u32*)(pw + lr * 272 + t * 32 + lq * 8 + 4) = w1;
      }
      // read back as B-operand frags: P^T[key=quad*8+j][q=lane&15]
#pragma unroll
      for (int ks = 0; ks < 4; ks++)
        pf[qt][ks] = *(const bf16x8*)(pw + lr * 272 + ks * 64 + lq * 16);
    }

    // out^T += Vt * P^T   (A=Vt frag, B=P frag)
#pragma unroll
    for (int dt = 0; dt < 5; dt++)
#pragma unroll
      for (int ks = 0; ks < 4; ks++) {
        bf16x8 vf = *(const bf16x8*)(ldsV + (dt * 4 + ks) * 1024 + lane * 16);
#pragma unroll
        for (int qt = 0; qt < 2; qt++)
          acc[qt][dt] = __builtin_amdgcn_mfma_f32_16x16x32_bf16(vf, pf[qt][ks], acc[qt][dt], 0, 0, 0);
      }
    __syncthreads();
  }

  // epilogue: out[q][d] = acc^T / l ; write bf16 [S][1280]
#pragma unroll
  for (int qt = 0; qt < 2; qt++) {
    float rl = 1.f / lsum[qt];
    int s = q0 + qt * 16 + lr;
#pragma unroll
    for (int dt = 0; dt < 5; dt++) {
      u32 w0 = (u32)f2b(acc[qt][dt][0] * rl) | ((u32)f2b(acc[qt][dt][1] * rl) << 16);
      u32 w1 = (u32)f2b(acc[qt][dt][2] * rl) | ((u32)f2b(acc[qt][dt][3] * rl) << 16);
      size_t ob = (size_t)s * HIDN + h * HD + dt * 16 + lq * 4;
      *(u32*)(Ob + ob) = w0;
      *(u32*)(Ob + ob + 2) = w1;
    }
  }
}

// ---------------- launch ----------------
extern "C" void kernel_launch(void* const* d_in, const int* in_sizes, int n_in,
                              void* d_out, int out_size, void* d_ws, size_t ws_size,
                              hipStream_t stream) {
  (void)in_sizes; (void)n_in; (void)out_size; (void)ws_size;
  const float* hidden = (const float*)d_in[0];
  const float* cosb   = (const float*)d_in[1];
  const float* sinb   = (const float*)d_in[2];
  const float* qkvk   = (const float*)d_in[3];
  const float* qkvb   = (const float*)d_in[4];
  const float* projk  = (const float*)d_in[5];
  const float* projb  = (const float*)d_in[6];
  // d_in[7] cu_seqlens: uniform windows, unused

  char* ws = (char*)d_ws;
  u16* Abf = (u16*)(ws + 0);          // 41,943,040 B ; reused as attn-out after gemm1
  u16* Wt  = (u16*)(ws + 41943040);   //  9,830,400 B
  u16* Pt  = (u16*)(ws + 51773440);   //  3,276,800 B
  u16* Qb  = (u16*)(ws + 55050240);   // 50,331,648 B
  u16* Kb  = (u16*)(ws + 105381888);  // 50,331,648 B
  u16* Vtb = (u16*)(ws + 155713536);  // 41,943,040 B -> total 197,656,576 B

  k_cvt<<<20480, 256, 0, stream>>>(hidden, Abf);
  k_trans<<<dim3(60, 20), 256, 0, stream>>>(qkvk, Wt, 1280, 3840);
  k_trans<<<dim3(20, 20), 256, 0, stream>>>(projk, Pt, 1280, 1280);
  k_gemm<1><<<dim3(30, 128), 256, 0, stream>>>(Abf, Wt, qkvb, nullptr, Qb, Kb, Vtb, 3840, 1280);
  k_rope<<<40960, 256, 0, stream>>>(Qb, cosb, sinb);
  k_rope<<<40960, 256, 0, stream>>>(Kb, cosb, sinb);
  k_attn<<<2048, 256, 0, stream>>>(Qb, Kb, Vtb, Abf);
  k_gemm<0><<<dim3(10, 128), 256, 0, stream>>>(Abf, Pt, projb, (float*)d_out,
                                               nullptr, nullptr, nullptr, 1280, 1280);
}

// Round 2
// 874.094 us; speedup vs baseline: 1.0401x; 1.0401x over previous
//
#include <hip/hip_runtime.h>
#include <stdint.h>

#define SEQ 16384
#define HIDN 1280
#define NHEADS 16
#define HD 80
#define HDP 96
#define NWIN 16
#define WINSZ 1024

typedef unsigned short u16;
typedef unsigned int u32;
typedef __bf16 bf16x8 __attribute__((ext_vector_type(8)));
typedef float f32x4 __attribute__((ext_vector_type(4)));

#define AS1 __attribute__((address_space(1)))
#define AS3 __attribute__((address_space(3)))

__device__ __forceinline__ u16 f2b(float f) {
  u32 u = __float_as_uint(f);
  u += 0x7fffu + ((u >> 16) & 1u);   // RNE
  return (u16)(u >> 16);
}
__device__ __forceinline__ float b2f(u16 u) { return __uint_as_float(((u32)u) << 16); }

__device__ __forceinline__ float fexp2(float x) {
#if __has_builtin(__builtin_amdgcn_exp2f)
  return __builtin_amdgcn_exp2f(x);
#else
  return exp2f(x);
#endif
}

__device__ __forceinline__ void load_lds16(const void* g, void* l) {
  __builtin_amdgcn_global_load_lds((AS1 void*)g, (AS3 void*)l, 16, 0, 0);
}

// ---------------- fp32 -> bf16 flat convert ----------------
__global__ void k_cvt(const float* __restrict__ in, u16* __restrict__ out) {
  size_t i = ((size_t)blockIdx.x * 256 + threadIdx.x) * 4;
  float4 v = *(const float4*)(in + i);
  uint2 o;
  o.x = (u32)f2b(v.x) | ((u32)f2b(v.y) << 16);
  o.y = (u32)f2b(v.z) | ((u32)f2b(v.w) << 16);
  *(uint2*)(out + i) = o;
}

// ---------------- transpose f32 [R][C] -> bf16 [C][R] ----------------
__global__ void k_trans(const float* __restrict__ in, u16* __restrict__ out, int R, int C) {
  __shared__ float tile[64][65];
  int c0 = blockIdx.x * 64, r0 = blockIdx.y * 64;
  int tc = threadIdx.x & 63, tr4 = threadIdx.x >> 6;
#pragma unroll
  for (int i = 0; i < 16; i++) {
    int r = tr4 + i * 4;
    tile[r][tc] = in[(size_t)(r0 + r) * C + c0 + tc];
  }
  __syncthreads();
#pragma unroll
  for (int i = 0; i < 16; i++) {
    int r = tr4 + i * 4;
    out[(size_t)(c0 + r) * R + r0 + tc] = f2b(tile[tc][r]);
  }
}

// ---------------- GEMM: C[M,N] = A[M,K](bf16) * B^T[N,K](bf16) + bias ----------------
// BK=64 (2 K-halves per barrier). 1D grid with octet swizzle:
//   id: x=id&7 (row-strip member), rest=id>>3, cb=rest%ncol, rs=rest/ncol
//   row-block = rs*8+x  -> 8 consecutive ids (typ. 8 XCDs) share col tile, own rows
// MODE 0: proj -> f32 out.  MODE 1: qkv -> scatter Q/K raw [H][S][96], V -> Vt [H][80][S]
template <int MODE>
__launch_bounds__(256, 2)
__global__ void k_gemm(const u16* __restrict__ A, const u16* __restrict__ B,
                       const float* __restrict__ bias, float* __restrict__ outf,
                       u16* __restrict__ Qb, u16* __restrict__ Kb, u16* __restrict__ Vt,
                       int N, int K, int ncol) {
  __shared__ char lds[32768];  // A-frags 16KB | B-frags 16KB
  const int tid = threadIdx.x;
  const int wv = tid >> 6, lane = tid & 63;
  const int lr = lane & 15, lq = lane >> 4;
  const int wm = wv >> 1, wn = wv & 1;
  const int id = blockIdx.x;
  const int xs = id & 7, rest = id >> 3;
  const int cb = rest % ncol, rs = rest / ncol;
  const int row0 = (rs * 8 + xs) * 128, col0 = cb * 128;

  f32x4 acc[4][4];
#pragma unroll
  for (int i = 0; i < 4; i++)
#pragma unroll
    for (int j = 0; j < 4; j++) acc[i][j] = (f32x4){0.f, 0.f, 0.f, 0.f};

  for (int kk = 0; kk < K; kk += 64) {
#pragma unroll
    for (int i = 0; i < 8; i++) {
      int g = wv * 8 + i;  // 0..31
      const u16* gp;
      char* lp;
      if (g < 16) {
        int t = g >> 1, h = g & 1;
        gp = A + (size_t)(row0 + t * 16 + lr) * K + kk + h * 32 + lq * 8;
        lp = lds + g * 1024;
      } else {
        int g2 = g - 16;
        int t = g2 >> 1, h = g2 & 1;
        gp = B + (size_t)(col0 + t * 16 + lr) * K + kk + h * 32 + lq * 8;
        lp = lds + 16384 + g2 * 1024;
      }
      load_lds16(gp, lp);
    }
    __syncthreads();
#pragma unroll
    for (int h = 0; h < 2; h++) {
      bf16x8 af[4], bfr[4];
#pragma unroll
      for (int mi = 0; mi < 4; mi++)
        af[mi] = *(const bf16x8*)(lds + ((wm * 4 + mi) * 2 + h) * 1024 + lane * 16);
#pragma unroll
      for (int ni = 0; ni < 4; ni++)
        bfr[ni] = *(const bf16x8*)(lds + 16384 + ((wn * 4 + ni) * 2 + h) * 1024 + lane * 16);
#pragma unroll
      for (int mi = 0; mi < 4; mi++)
#pragma unroll
        for (int ni = 0; ni < 4; ni++)
          acc[mi][ni] = __builtin_amdgcn_mfma_f32_16x16x32_bf16(af[mi], bfr[ni], acc[mi][ni], 0, 0, 0);
    }
    __syncthreads();
  }

  // epilogue: C/D layout col=lane&15, row=(lane>>4)*4+reg (m89-verified)
#pragma unroll
  for (int ni = 0; ni < 4; ni++) {
    int col = col0 + wn * 64 + ni * 16 + lr;
    float bs = bias[col];
    if (MODE == 0) {
#pragma unroll
      for (int mi = 0; mi < 4; mi++)
#pragma unroll
        for (int r = 0; r < 4; r++) {
          int row = row0 + wm * 64 + mi * 16 + lq * 4 + r;
          outf[(size_t)row * N + col] = acc[mi][ni][r] + bs;
        }
    } else {
      int seg = col / HIDN;            // 0=q 1=k 2=v (uniform per 16-col tile: 1280%16==0)
      int cl = col - seg * HIDN;
      int h = cl / HD, d = cl - h * HD;
#pragma unroll
      for (int mi = 0; mi < 4; mi++)
#pragma unroll
        for (int r = 0; r < 4; r++) {
          int row = row0 + wm * 64 + mi * 16 + lq * 4 + r;
          u16 bv = f2b(acc[mi][ni][r] + bs);
          if (seg == 0)
            Qb[((size_t)h * SEQ + row) * HDP + d] = bv;
          else if (seg == 1)
            Kb[((size_t)h * SEQ + row) * HDP + d] = bv;
          else
            Vt[((size_t)h * HD + d) * SEQ + row] = bv;
        }
    }
  }
}

// ---------------- in-place RoPE on [H][S][96] bf16, zero pad d in [80,96) ----------------
__global__ void k_rope(u16* __restrict__ X, const float* __restrict__ cs, const float* __restrict__ sn) {
  int idx = blockIdx.x * 256 + threadIdx.x;  // [0, 16*16384*40)
  int h = idx / (SEQ * 40);
  int rem = idx - h * (SEQ * 40);
  int s = rem / 40;
  int d = rem - s * 40;
  size_t base = ((size_t)h * SEQ + s) * HDP;
  float c = cs[s * HD + d], si = sn[s * HD + d];  // cos[d]==cos[d+40]
  float x1 = b2f(X[base + d]), x2 = b2f(X[base + d + 40]);
  X[base + d] = f2b(x1 * c - x2 * si);
  X[base + d + 40] = f2b(x2 * c + x1 * si);
  if (d < 16) X[base + 80 + d] = 0;
}

// ---------------- windowed flash attention ----------------
// Q,K: [H][S][96] bf16 (rope'd, pad=0); Vt: [H][80][S] bf16; Ob: [S][1280] bf16
// block: 256 thr = 4 waves, each wave: 32 q (2 tiles), k-tiles of 128 keys
__launch_bounds__(256, 2)
__global__ void k_attn(const u16* __restrict__ Qb, const u16* __restrict__ Kb,
                       const u16* __restrict__ Vt, u16* __restrict__ Ob) {
  __shared__ char lds[24576 + 20480 + 4 * 4352];
  char* ldsK = lds;
  char* ldsV = lds + 24576;
  char* ldsP = lds + 45056;

  const int tid = threadIdx.x;
  const int wv = tid >> 6, lane = tid & 63;
  const int lr = lane & 15, lq = lane >> 4;

  const int b = blockIdx.x;
  const int qblk = b & 7, h = (b >> 3) & 15, w = b >> 7;
  const int q0 = w * WINSZ + qblk * 128 + wv * 32;
  const int kwin = w * WINSZ;

  // resident Q fragments (B-operand of S^T = K*Q^T): Q[q=lane&15][d=quad*8+j]
  bf16x8 qf[2][3];
#pragma unroll
  for (int qt = 0; qt < 2; qt++)
#pragma unroll
    for (int ds = 0; ds < 3; ds++)
      qf[qt][ds] = *(const bf16x8*)(Qb + ((size_t)h * SEQ + q0 + qt * 16 + lr) * HDP + ds * 32 + lq * 8);

  f32x4 acc[2][5];
#pragma unroll
  for (int i = 0; i < 2; i++)
#pragma unroll
    for (int j = 0; j < 5; j++) acc[i][j] = (f32x4){0.f, 0.f, 0.f, 0.f};
  float mo[2] = {-1e30f, -1e30f};
  float lsum[2] = {0.f, 0.f};
  const float kscale = 0.11180339887498949f * 1.4426950408889634f;  // 1/sqrt(80) * log2(e)

  for (int kt = 0; kt < 8; kt++) {
    int k0 = kwin + kt * 128;
    // stage K-tile (24 KB) + Vt-tile (20 KB) in fragment order
#pragma unroll
    for (int li = 0; li < 11; li++) {
      int g = li * 4 + wv;
      const u16* gp;
      char* lp;
      if (g < 24) {
        int kt16 = g / 3, ds = g - kt16 * 3;
        gp = Kb + ((size_t)h * SEQ + k0 + kt16 * 16 + lr) * HDP + ds * 32 + lq * 8;
        lp = ldsK + g * 1024;
      } else {
        int g2 = g - 24;
        int dt = g2 >> 2, ks = g2 & 3;
        gp = Vt + ((size_t)h * HD + dt * 16 + lr) * SEQ + k0 + ks * 32 + lq * 8;
        lp = ldsV + g2 * 1024;
      }
      load_lds16(gp, lp);
    }
    __syncthreads();

    // S^T = K*Q^T  (A=K frag, B=Q frag); S^T[key=quad*4+reg][q=lane&15]
    f32x4 sx[2][8];
#pragma unroll
    for (int i = 0; i < 2; i++)
#pragma unroll
      for (int j = 0; j < 8; j++) sx[i][j] = (f32x4){0.f, 0.f, 0.f, 0.f};
#pragma unroll
    for (int kt16 = 0; kt16 < 8; kt16++) {
      bf16x8 kf0 = *(const bf16x8*)(ldsK + (kt16 * 3 + 0) * 1024 + lane * 16);
      bf16x8 kf1 = *(const bf16x8*)(ldsK + (kt16 * 3 + 1) * 1024 + lane * 16);
      bf16x8 kf2 = *(const bf16x8*)(ldsK + (kt16 * 3 + 2) * 1024 + lane * 16);
#pragma unroll
      for (int qt = 0; qt < 2; qt++) {
        sx[qt][kt16] = __builtin_amdgcn_mfma_f32_16x16x32_bf16(kf0, qf[qt][0], sx[qt][kt16], 0, 0, 0);
        sx[qt][kt16] = __builtin_amdgcn_mfma_f32_16x16x32_bf16(kf1, qf[qt][1], sx[qt][kt16], 0, 0, 0);
        sx[qt][kt16] = __builtin_amdgcn_mfma_f32_16x16x32_bf16(kf2, qf[qt][2], sx[qt][kt16], 0, 0, 0);
      }
    }

    // online softmax (per-lane column q; cross-quad reduce via xor 16/32) + P->LDS->B-frags
    bf16x8 pf[2][4];
#pragma unroll
    for (int qt = 0; qt < 2; qt++) {
      float mx = -1e30f;
#pragma unroll
      for (int t = 0; t < 8; t++)
#pragma unroll
        for (int r = 0; r < 4; r++) mx = fmaxf(mx, sx[qt][t][r]);
      mx = fmaxf(mx, __shfl_xor(mx, 16));
      mx = fmaxf(mx, __shfl_xor(mx, 32));
      float mnew = fmaxf(mo[qt], mx * kscale);
      float alpha = fexp2(mo[qt] - mnew);
      mo[qt] = mnew;
      float ls = 0.f;
#pragma unroll
      for (int t = 0; t < 8; t++)
#pragma unroll
        for (int r = 0; r < 4; r++) {
          float p = fexp2(fmaf(sx[qt][t][r], kscale, -mnew));
          sx[qt][t][r] = p;
          ls += p;
        }
      ls += __shfl_xor(ls, 16);
      ls += __shfl_xor(ls, 32);
      lsum[qt] = lsum[qt] * alpha + ls;
#pragma unroll
      for (int dt = 0; dt < 5; dt++) acc[qt][dt] *= alpha;
      // write P (bf16) to per-wave LDS: rows q (stride 272B), cols key
      char* pw = ldsP + wv * 4352;
#pragma unroll
      for (int t = 0; t < 8; t++) {
        u32 w0 = (u32)f2b(sx[qt][t][0]) | ((u32)f2b(sx[qt][t][1]) << 16);
        u32 w1 = (u32)f2b(sx[qt][t][2]) | ((u32)f2b(sx[qt][t][3]) << 16);
        *(u32*)(pw + lr * 272 + t * 32 + lq * 8) = w0;
        *(u32*)(pw + lr * 272 + t * 32 + lq * 8 + 4) = w1;
      }
      // read back as B-operand frags: P^T[key=quad*8+j][q=lane&15]
#pragma unroll
      for (int ks = 0; ks < 4; ks++)
        pf[qt][ks] = *(const bf16x8*)(pw + lr * 272 + ks * 64 + lq * 16);
    }

    // out^T += Vt * P^T   (A=Vt frag, B=P frag)
#pragma unroll
    for (int dt = 0; dt < 5; dt++)
#pragma unroll
      for (int ks = 0; ks < 4; ks++) {
        bf16x8 vf = *(const bf16x8*)(ldsV + (dt * 4 + ks) * 1024 + lane * 16);
#pragma unroll
        for (int qt = 0; qt < 2; qt++)
          acc[qt][dt] = __builtin_amdgcn_mfma_f32_16x16x32_bf16(vf, pf[qt][ks], acc[qt][dt], 0, 0, 0);
      }
    __syncthreads();
  }

  // epilogue: out[q][d] = acc^T / l ; write bf16 [S][1280]
#pragma unroll
  for (int qt = 0; qt < 2; qt++) {
    float rl = 1.f / lsum[qt];
    int s = q0 + qt * 16 + lr;
#pragma unroll
    for (int dt = 0; dt < 5; dt++) {
      u32 w0 = (u32)f2b(acc[qt][dt][0] * rl) | ((u32)f2b(acc[qt][dt][1] * rl) << 16);
      u32 w1 = (u32)f2b(acc[qt][dt][2] * rl) | ((u32)f2b(acc[qt][dt][3] * rl) << 16);
      size_t ob = (size_t)s * HIDN + h * HD + dt * 16 + lq * 4;
      *(u32*)(Ob + ob) = w0;
      *(u32*)(Ob + ob + 2) = w1;
    }
  }
}

// ---------------- launch ----------------
extern "C" void kernel_launch(void* const* d_in, const int* in_sizes, int n_in,
                              void* d_out, int out_size, void* d_ws, size_t ws_size,
                              hipStream_t stream) {
  (void)in_sizes; (void)n_in; (void)out_size; (void)ws_size;
  const float* hidden = (const float*)d_in[0];
  const float* cosb   = (const float*)d_in[1];
  const float* sinb   = (const float*)d_in[2];
  const float* qkvk   = (const float*)d_in[3];
  const float* qkvb   = (const float*)d_in[4];
  const float* projk  = (const float*)d_in[5];
  const float* projb  = (const float*)d_in[6];
  // d_in[7] cu_seqlens: uniform windows, unused

  char* ws = (char*)d_ws;
  u16* Abf = (u16*)(ws + 0);          // 41,943,040 B ; reused as attn-out after gemm1
  u16* Wt  = (u16*)(ws + 41943040);   //  9,830,400 B
  u16* Pt  = (u16*)(ws + 51773440);   //  3,276,800 B
  u16* Qb  = (u16*)(ws + 55050240);   // 50,331,648 B
  u16* Kb  = (u16*)(ws + 105381888);  // 50,331,648 B
  u16* Vtb = (u16*)(ws + 155713536);  // 41,943,040 B -> total 197,656,576 B

  k_cvt<<<20480, 256, 0, stream>>>(hidden, Abf);
  k_trans<<<dim3(60, 20), 256, 0, stream>>>(qkvk, Wt, 1280, 3840);
  k_trans<<<dim3(20, 20), 256, 0, stream>>>(projk, Pt, 1280, 1280);
  k_gemm<1><<<3840, 256, 0, stream>>>(Abf, Wt, qkvb, nullptr, Qb, Kb, Vtb, 3840, 1280, 30);
  k_rope<<<40960, 256, 0, stream>>>(Qb, cosb, sinb);
  k_rope<<<40960, 256, 0, stream>>>(Kb, cosb, sinb);
  k_attn<<<2048, 256, 0, stream>>>(Qb, Kb, Vtb, Abf);
  k_gemm<0><<<1280, 256, 0, stream>>>(Abf, Pt, projb, (float*)d_out,
                                      nullptr, nullptr, nullptr, 1280, 1280, 10);
}

// Round 3
// 845.942 us; speedup vs baseline: 1.0747x; 1.0333x over previous
//
#include <hip/hip_runtime.h>
#include <stdint.h>

#define SEQ 16384
#define HIDN 1280
#define NHEADS 16
#define HD 80
#define HDP 96
#define NWIN 16
#define WINSZ 1024

typedef unsigned short u16;
typedef unsigned int u32;
typedef __bf16 bf16x8 __attribute__((ext_vector_type(8)));
typedef float f32x4 __attribute__((ext_vector_type(4)));

#define AS1 __attribute__((address_space(1)))
#define AS3 __attribute__((address_space(3)))

__device__ __forceinline__ u16 f2b(float f) {
  u32 u = __float_as_uint(f);
  u += 0x7fffu + ((u >> 16) & 1u);   // RNE
  return (u16)(u >> 16);
}
__device__ __forceinline__ float b2f(u16 u) { return __uint_as_float(((u32)u) << 16); }

__device__ __forceinline__ float fexp2(float x) {
#if __has_builtin(__builtin_amdgcn_exp2f)
  return __builtin_amdgcn_exp2f(x);
#else
  return exp2f(x);
#endif
}

__device__ __forceinline__ void load_lds16(const void* g, void* l) {
  __builtin_amdgcn_global_load_lds((AS1 void*)g, (AS3 void*)l, 16, 0, 0);
}

// ---------------- fp32 -> bf16 flat convert ----------------
__global__ void k_cvt(const float* __restrict__ in, u16* __restrict__ out) {
  size_t i = ((size_t)blockIdx.x * 256 + threadIdx.x) * 4;
  float4 v = *(const float4*)(in + i);
  uint2 o;
  o.x = (u32)f2b(v.x) | ((u32)f2b(v.y) << 16);
  o.y = (u32)f2b(v.z) | ((u32)f2b(v.w) << 16);
  *(uint2*)(out + i) = o;
}

// ---------------- transpose f32 [R][C] -> bf16 [C][R] ----------------
__global__ void k_trans(const float* __restrict__ in, u16* __restrict__ out, int R, int C) {
  __shared__ float tile[64][65];
  int c0 = blockIdx.x * 64, r0 = blockIdx.y * 64;
  int tc = threadIdx.x & 63, tr4 = threadIdx.x >> 6;
#pragma unroll
  for (int i = 0; i < 16; i++) {
    int r = tr4 + i * 4;
    tile[r][tc] = in[(size_t)(r0 + r) * C + c0 + tc];
  }
  __syncthreads();
#pragma unroll
  for (int i = 0; i < 16; i++) {
    int r = tr4 + i * 4;
    out[(size_t)(c0 + r) * R + r0 + tc] = f2b(tile[tc][r]);
  }
}

// ---------------- GEMM: C[M,N] = A[M,K](bf16) * B^T[N,K](bf16) + bias ----------------
// 256x256 tile, 1024 threads = 16 waves of 64x64. BK=32, double-buffered LDS
// (2 x 32KB), ONE barrier per K-step: barrier = (my staging loads drained via
// vmcnt) AND (everyone done reading the buffer about to be overwritten).
// Octet swizzle: 8 consecutive ids (~8 XCDs) share col-tile, own row-strips.
// MODE 0: proj -> f32 out.  MODE 1: qkv -> scatter Q/K raw [H][S][96], V -> Vt [H][80][S]
template <int MODE>
__launch_bounds__(1024, 4)
__global__ void k_gemm(const u16* __restrict__ A, const u16* __restrict__ B,
                       const float* __restrict__ bias, float* __restrict__ outf,
                       u16* __restrict__ Qb, u16* __restrict__ Kb, u16* __restrict__ Vt,
                       int N, int K, int ncol) {
  __shared__ char lds[65536];  // [buf][A 16KB | B 16KB]
  const int tid = threadIdx.x;
  const int wv = tid >> 6, lane = tid & 63;
  const int lr = lane & 15, lq = lane >> 4;
  const int wm = wv >> 2, wn = wv & 3;
  const int id = blockIdx.x;
  const int xs = id & 7, rest = id >> 3;
  const int cb = rest % ncol, rs = rest / ncol;
  const int row0 = (rs * 8 + xs) * 256, col0 = cb * 256;

  // staging assignment: wave wv stages tiles {2wv, 2wv+1}; tiles 0..15 = A
  // row-tiles, 16..31 = B col-tiles. 1KB per tile, fragment order lane*16.
  const int g0 = 2 * wv, g1 = 2 * wv + 1;
  const u16* gsrc[2];
  int loff[2];
#pragma unroll
  for (int i = 0; i < 2; i++) {
    int g = 2 * wv + i;
    if (g < 16) {
      gsrc[i] = A + (size_t)(row0 + g * 16 + lr) * K + lq * 8;
      loff[i] = g * 1024 + lane * 16;
    } else {
      gsrc[i] = B + (size_t)(col0 + (g - 16) * 16 + lr) * K + lq * 8;
      loff[i] = 16384 + (g - 16) * 1024 + lane * 16;
    }
  }
  (void)g0; (void)g1;

  f32x4 acc[4][4];
#pragma unroll
  for (int i = 0; i < 4; i++)
#pragma unroll
    for (int j = 0; j < 4; j++) acc[i][j] = (f32x4){0.f, 0.f, 0.f, 0.f};

  const int nk = K >> 5;  // BK=32
  // prologue: stage k-step 0 into buf 0
#pragma unroll
  for (int i = 0; i < 2; i++) load_lds16(gsrc[i], lds + loff[i]);

  int buf = 0;
  for (int it = 0; it < nk; it++) {
    __syncthreads();  // buf ready (vmcnt drained per-wave) + prior reads done
    if (it + 1 < nk) {
      int koff = (it + 1) * 32;
#pragma unroll
      for (int i = 0; i < 2; i++)
        load_lds16(gsrc[i] + koff, lds + (buf ^ 1) * 32768 + loff[i]);
    }
    const char* la = lds + buf * 32768;
    bf16x8 af[4], bfr[4];
#pragma unroll
    for (int mi = 0; mi < 4; mi++)
      af[mi] = *(const bf16x8*)(la + (wm * 4 + mi) * 1024 + lane * 16);
#pragma unroll
    for (int ni = 0; ni < 4; ni++)
      bfr[ni] = *(const bf16x8*)(la + 16384 + (wn * 4 + ni) * 1024 + lane * 16);
#pragma unroll
    for (int mi = 0; mi < 4; mi++)
#pragma unroll
      for (int ni = 0; ni < 4; ni++)
        acc[mi][ni] = __builtin_amdgcn_mfma_f32_16x16x32_bf16(af[mi], bfr[ni], acc[mi][ni], 0, 0, 0);
    buf ^= 1;
  }

  // epilogue: C/D layout col=lane&15, row=(lane>>4)*4+reg (m89-verified)
#pragma unroll
  for (int ni = 0; ni < 4; ni++) {
    int col = col0 + wn * 64 + ni * 16 + lr;
    float bs = bias[col];
    if (MODE == 0) {
#pragma unroll
      for (int mi = 0; mi < 4; mi++)
#pragma unroll
        for (int r = 0; r < 4; r++) {
          int row = row0 + wm * 64 + mi * 16 + lq * 4 + r;
          outf[(size_t)row * N + col] = acc[mi][ni][r] + bs;
        }
    } else {
      int seg = col / HIDN;            // 0=q 1=k 2=v (uniform per 16-col tile: 1280%16==0)
      int cl = col - seg * HIDN;
      int h = cl / HD, d = cl - h * HD;
#pragma unroll
      for (int mi = 0; mi < 4; mi++)
#pragma unroll
        for (int r = 0; r < 4; r++) {
          int row = row0 + wm * 64 + mi * 16 + lq * 4 + r;
          u16 bv = f2b(acc[mi][ni][r] + bs);
          if (seg == 0)
            Qb[((size_t)h * SEQ + row) * HDP + d] = bv;
          else if (seg == 1)
            Kb[((size_t)h * SEQ + row) * HDP + d] = bv;
          else
            Vt[((size_t)h * HD + d) * SEQ + row] = bv;
        }
    }
  }
}

// ---------------- in-place RoPE on [H][S][96] bf16, zero pad d in [80,96) ----------------
__global__ void k_rope(u16* __restrict__ X, const float* __restrict__ cs, const float* __restrict__ sn) {
  int idx = blockIdx.x * 256 + threadIdx.x;  // [0, 16*16384*40)
  int h = idx / (SEQ * 40);
  int rem = idx - h * (SEQ * 40);
  int s = rem / 40;
  int d = rem - s * 40;
  size_t base = ((size_t)h * SEQ + s) * HDP;
  float c = cs[s * HD + d], si = sn[s * HD + d];  // cos[d]==cos[d+40]
  float x1 = b2f(X[base + d]), x2 = b2f(X[base + d + 40]);
  X[base + d] = f2b(x1 * c - x2 * si);
  X[base + d + 40] = f2b(x2 * c + x1 * si);
  if (d < 16) X[base + 80 + d] = 0;
}

// ---------------- windowed flash attention ----------------
// Q,K: [H][S][96] bf16 (rope'd, pad=0); Vt: [H][80][S] bf16; Ob: [S][1280] bf16
// block: 256 thr = 4 waves, each wave: 32 q (2 tiles), k-tiles of 128 keys
__launch_bounds__(256, 2)
__global__ void k_attn(const u16* __restrict__ Qb, const u16* __restrict__ Kb,
                       const u16* __restrict__ Vt, u16* __restrict__ Ob) {
  __shared__ char lds[24576 + 20480 + 4 * 4352];
  char* ldsK = lds;
  char* ldsV = lds + 24576;
  char* ldsP = lds + 45056;

  const int tid = threadIdx.x;
  const int wv = tid >> 6, lane = tid & 63;
  const int lr = lane & 15, lq = lane >> 4;

  const int b = blockIdx.x;
  const int qblk = b & 7, h = (b >> 3) & 15, w = b >> 7;
  const int q0 = w * WINSZ + qblk * 128 + wv * 32;
  const int kwin = w * WINSZ;

  // resident Q fragments (B-operand of S^T = K*Q^T): Q[q=lane&15][d=quad*8+j]
  bf16x8 qf[2][3];
#pragma unroll
  for (int qt = 0; qt < 2; qt++)
#pragma unroll
    for (int ds = 0; ds < 3; ds++)
      qf[qt][ds] = *(const bf16x8*)(Qb + ((size_t)h * SEQ + q0 + qt * 16 + lr) * HDP + ds * 32 + lq * 8);

  f32x4 acc[2][5];
#pragma unroll
  for (int i = 0; i < 2; i++)
#pragma unroll
    for (int j = 0; j < 5; j++) acc[i][j] = (f32x4){0.f, 0.f, 0.f, 0.f};
  float mo[2] = {-1e30f, -1e30f};
  float lsum[2] = {0.f, 0.f};
  const float kscale = 0.11180339887498949f * 1.4426950408889634f;  // 1/sqrt(80) * log2(e)

  for (int kt = 0; kt < 8; kt++) {
    int k0 = kwin + kt * 128;
    // stage K-tile (24 KB) + Vt-tile (20 KB) in fragment order
#pragma unroll
    for (int li = 0; li < 11; li++) {
      int g = li * 4 + wv;
      const u16* gp;
      char* lp;
      if (g < 24) {
        int kt16 = g / 3, ds = g - kt16 * 3;
        gp = Kb + ((size_t)h * SEQ + k0 + kt16 * 16 + lr) * HDP + ds * 32 + lq * 8;
        lp = ldsK + g * 1024;
      } else {
        int g2 = g - 24;
        int dt = g2 >> 2, ks = g2 & 3;
        gp = Vt + ((size_t)h * HD + dt * 16 + lr) * SEQ + k0 + ks * 32 + lq * 8;
        lp = ldsV + g2 * 1024;
      }
      load_lds16(gp, lp);
    }
    __syncthreads();

    // S^T = K*Q^T  (A=K frag, B=Q frag); S^T[key=quad*4+reg][q=lane&15]
    f32x4 sx[2][8];
#pragma unroll
    for (int i = 0; i < 2; i++)
#pragma unroll
      for (int j = 0; j < 8; j++) sx[i][j] = (f32x4){0.f, 0.f, 0.f, 0.f};
#pragma unroll
    for (int kt16 = 0; kt16 < 8; kt16++) {
      bf16x8 kf0 = *(const bf16x8*)(ldsK + (kt16 * 3 + 0) * 1024 + lane * 16);
      bf16x8 kf1 = *(const bf16x8*)(ldsK + (kt16 * 3 + 1) * 1024 + lane * 16);
      bf16x8 kf2 = *(const bf16x8*)(ldsK + (kt16 * 3 + 2) * 1024 + lane * 16);
#pragma unroll
      for (int qt = 0; qt < 2; qt++) {
        sx[qt][kt16] = __builtin_amdgcn_mfma_f32_16x16x32_bf16(kf0, qf[qt][0], sx[qt][kt16], 0, 0, 0);
        sx[qt][kt16] = __builtin_amdgcn_mfma_f32_16x16x32_bf16(kf1, qf[qt][1], sx[qt][kt16], 0, 0, 0);
        sx[qt][kt16] = __builtin_amdgcn_mfma_f32_16x16x32_bf16(kf2, qf[qt][2], sx[qt][kt16], 0, 0, 0);
      }
    }

    // online softmax (per-lane column q; cross-quad reduce via xor 16/32) + P->LDS->B-frags
    bf16x8 pf[2][4];
#pragma unroll
    for (int qt = 0; qt < 2; qt++) {
      float mx = -1e30f;
#pragma unroll
      for (int t = 0; t < 8; t++)
#pragma unroll
        for (int r = 0; r < 4; r++) mx = fmaxf(mx, sx[qt][t][r]);
      mx = fmaxf(mx, __shfl_xor(mx, 16));
      mx = fmaxf(mx, __shfl_xor(mx, 32));
      float mnew = fmaxf(mo[qt], mx * kscale);
      float alpha = fexp2(mo[qt] - mnew);
      mo[qt] = mnew;
      float ls = 0.f;
#pragma unroll
      for (int t = 0; t < 8; t++)
#pragma unroll
        for (int r = 0; r < 4; r++) {
          float p = fexp2(fmaf(sx[qt][t][r], kscale, -mnew));
          sx[qt][t][r] = p;
          ls += p;
        }
      ls += __shfl_xor(ls, 16);
      ls += __shfl_xor(ls, 32);
      lsum[qt] = lsum[qt] * alpha + ls;
#pragma unroll
      for (int dt = 0; dt < 5; dt++) acc[qt][dt] *= alpha;
      // write P (bf16) to per-wave LDS: rows q (stride 272B), cols key
      char* pw = ldsP + wv * 4352;
#pragma unroll
      for (int t = 0; t < 8; t++) {
        u32 w0 = (u32)f2b(sx[qt][t][0]) | ((u32)f2b(sx[qt][t][1]) << 16);
        u32 w1 = (u32)f2b(sx[qt][t][2]) | ((u32)f2b(sx[qt][t][3]) << 16);
        *(u32*)(pw + lr * 272 + t * 32 + lq * 8) = w0;
        *(u32*)(pw + lr * 272 + t * 32 + lq * 8 + 4) = w1;
      }
      // read back as B-operand frags: P^T[key=quad*8+j][q=lane&15]
#pragma unroll
      for (int ks = 0; ks < 4; ks++)
        pf[qt][ks] = *(const bf16x8*)(pw + lr * 272 + ks * 64 + lq * 16);
    }

    // out^T += Vt * P^T   (A=Vt frag, B=P frag)
#pragma unroll
    for (int dt = 0; dt < 5; dt++)
#pragma unroll
      for (int ks = 0; ks < 4; ks++) {
        bf16x8 vf = *(const bf16x8*)(ldsV + (dt * 4 + ks) * 1024 + lane * 16);
#pragma unroll
        for (int qt = 0; qt < 2; qt++)
          acc[qt][dt] = __builtin_amdgcn_mfma_f32_16x16x32_bf16(vf, pf[qt][ks], acc[qt][dt], 0, 0, 0);
      }
    __syncthreads();
  }

  // epilogue: out[q][d] = acc^T / l ; write bf16 [S][1280]
#pragma unroll
  for (int qt = 0; qt < 2; qt++) {
    float rl = 1.f / lsum[qt];
    int s = q0 + qt * 16 + lr;
#pragma unroll
    for (int dt = 0; dt < 5; dt++) {
      u32 w0 = (u32)f2b(acc[qt][dt][0] * rl) | ((u32)f2b(acc[qt][dt][1] * rl) << 16);
      u32 w1 = (u32)f2b(acc[qt][dt][2] * rl) | ((u32)f2b(acc[qt][dt][3] * rl) << 16);
      size_t ob = (size_t)s * HIDN + h * HD + dt * 16 + lq * 4;
      *(u32*)(Ob + ob) = w0;
      *(u32*)(Ob + ob + 2) = w1;
    }
  }
}

// ---------------- launch ----------------
extern "C" void kernel_launch(void* const* d_in, const int* in_sizes, int n_in,
                              void* d_out, int out_size, void* d_ws, size_t ws_size,
                              hipStream_t stream) {
  (void)in_sizes; (void)n_in; (void)out_size; (void)ws_size;
  const float* hidden = (const float*)d_in[0];
  const float* cosb   = (const float*)d_in[1];
  const float* sinb   = (const float*)d_in[2];
  const float* qkvk   = (const float*)d_in[3];
  const float* qkvb   = (const float*)d_in[4];
  const float* projk  = (const float*)d_in[5];
  const float* projb  = (const float*)d_in[6];
  // d_in[7] cu_seqlens: uniform windows, unused

  char* ws = (char*)d_ws;
  u16* Abf = (u16*)(ws + 0);          // 41,943,040 B ; reused as attn-out after gemm1
  u16* Wt  = (u16*)(ws + 41943040);   //  9,830,400 B
  u16* Pt  = (u16*)(ws + 51773440);   //  3,276,800 B
  u16* Qb  = (u16*)(ws + 55050240);   // 50,331,648 B
  u16* Kb  = (u16*)(ws + 105381888);  // 50,331,648 B
  u16* Vtb = (u16*)(ws + 155713536);  // 41,943,040 B -> total 197,656,576 B

  k_cvt<<<20480, 256, 0, stream>>>(hidden, Abf);
  k_trans<<<dim3(60, 20), 256, 0, stream>>>(qkvk, Wt, 1280, 3840);
  k_trans<<<dim3(20, 20), 256, 0, stream>>>(projk, Pt, 1280, 1280);
  // qkv: M=16384 N=3840 -> 64 x 15 tiles of 256x256 = 960 blocks
  k_gemm<1><<<960, 1024, 0, stream>>>(Abf, Wt, qkvb, nullptr, Qb, Kb, Vtb, 3840, 1280, 15);
  k_rope<<<40960, 256, 0, stream>>>(Qb, cosb, sinb);
  k_rope<<<40960, 256, 0, stream>>>(Kb, cosb, sinb);
  k_attn<<<2048, 256, 0, stream>>>(Qb, Kb, Vtb, Abf);
  // proj: M=16384 N=1280 -> 64 x 5 tiles of 256x256 = 320 blocks
  k_gemm<0><<<320, 1024, 0, stream>>>(Abf, Pt, projb, (float*)d_out,
                                      nullptr, nullptr, nullptr, 1280, 1280, 5);
}